// Round 1
// baseline (763.807 us; speedup 1.0000x reference)
//
#include <hip/hip_runtime.h>
#include <math.h>

#define D 128
#define OUTD 64

// ---------------- CSR build ----------------

__global__ void k_hist(const int* __restrict__ ei, int* __restrict__ deg, int E) {
  int e = blockIdx.x * 256 + threadIdx.x;
  if (e < E) atomicAdd(&deg[ei[E + e]], 1);
}

__global__ __launch_bounds__(1024) void k_scan(const int* __restrict__ deg,
                                               int* __restrict__ offs, int N) {
  __shared__ int wsum[16];
  __shared__ int s_carry;
  int tid = threadIdx.x, lane = tid & 63, wv = tid >> 6;
  if (tid == 0) s_carry = 0;
  __syncthreads();
  for (int base = 0; base < N; base += 1024) {
    int i = base + tid;
    int v = (i < N) ? deg[i] : 0;
    int x = v;
#pragma unroll
    for (int off = 1; off < 64; off <<= 1) {
      int t = __shfl_up(x, off);
      if (lane >= off) x += t;
    }
    if (lane == 63) wsum[wv] = x;
    __syncthreads();
    if (wv == 0) {
      int s = (lane < 16) ? wsum[lane] : 0;
#pragma unroll
      for (int off = 1; off < 16; off <<= 1) {
        int t = __shfl_up(s, off);
        if (lane >= off) s += t;
      }
      if (lane < 16) wsum[lane] = s;
    }
    __syncthreads();
    int wexcl = (wv == 0) ? 0 : wsum[wv - 1];
    int excl = s_carry + wexcl + x - v;
    if (i < N) offs[i] = excl;
    __syncthreads();
    if (tid == 1023) s_carry += wsum[15];
    __syncthreads();
  }
  if (tid == 0) offs[N] = s_carry;
}

__global__ void k_copy(const int* __restrict__ a, int* __restrict__ b, int n) {
  int i = blockIdx.x * 256 + threadIdx.x;
  if (i < n) b[i] = a[i];
}

__global__ void k_fill(const int* __restrict__ ei, int* __restrict__ cursor,
                       int* __restrict__ csr_src, int E) {
  int e = blockIdx.x * 256 + threadIdx.x;
  if (e < E) {
    int d = ei[E + e];
    int pos = atomicAdd(&cursor[d], 1);
    csr_src[pos] = ei[e];
  }
}

// ---------------- GEMM: C[M x 128] = A[M x 128] @ W[128 x 128] + bias ----------------
// block 256 threads, 32-row tile, K tiled in 4 chunks of 32 staged in LDS.

__global__ __launch_bounds__(256) void k_gemm128(const float* __restrict__ A,
                                                 const float* __restrict__ W,
                                                 const float* __restrict__ bias,
                                                 float* __restrict__ C, int M) {
  __shared__ float xs[32 * 128];
  __shared__ float ws[32 * 128];
  int tid = threadIdx.x;
  int row0 = blockIdx.x * 32;

  const float4* A4 = (const float4*)A;
  float4* xs4 = (float4*)xs;
#pragma unroll
  for (int i = 0; i < 4; ++i) {
    int idx = tid + 256 * i;          // 0..1023
    int r = idx >> 5, c4 = idx & 31;
    int gr = row0 + r;
    xs4[idx] = (gr < M) ? A4[(size_t)gr * 32 + c4] : make_float4(0.f, 0.f, 0.f, 0.f);
  }

  int cgrp = tid & 15;   // cols cgrp*8 .. +7
  int rgrp = tid >> 4;   // rows rgrp*2, rgrp*2+1
  const float* xr0 = xs + (rgrp * 2) * 128;
  const float* xr1 = xr0 + 128;

  float acc0[8] = {0, 0, 0, 0, 0, 0, 0, 0};
  float acc1[8] = {0, 0, 0, 0, 0, 0, 0, 0};

  const float4* W4 = (const float4*)W;
  float4* ws4 = (float4*)ws;

  for (int kt = 0; kt < 4; ++kt) {
    __syncthreads();
#pragma unroll
    for (int i = 0; i < 4; ++i) {
      int idx = tid + 256 * i;        // 0..1023 float4 of this 32x128 tile
      ws4[idx] = W4[kt * 1024 + idx];
    }
    __syncthreads();
#pragma unroll
    for (int kk = 0; kk < 32; ++kk) {
      int k = kt * 32 + kk;
      float a0 = xr0[k];
      float a1 = xr1[k];
      const float4* wk = (const float4*)(ws + kk * 128 + cgrp * 8);
      float4 w0 = wk[0], w1 = wk[1];
      acc0[0] += a0 * w0.x; acc0[1] += a0 * w0.y; acc0[2] += a0 * w0.z; acc0[3] += a0 * w0.w;
      acc0[4] += a0 * w1.x; acc0[5] += a0 * w1.y; acc0[6] += a0 * w1.z; acc0[7] += a0 * w1.w;
      acc1[0] += a1 * w0.x; acc1[1] += a1 * w0.y; acc1[2] += a1 * w0.z; acc1[3] += a1 * w0.w;
      acc1[4] += a1 * w1.x; acc1[5] += a1 * w1.y; acc1[6] += a1 * w1.z; acc1[7] += a1 * w1.w;
    }
  }

  const float4* b4 = (const float4*)(bias + cgrp * 8);
  float4 b0 = b4[0], b1 = b4[1];
  float4* C4 = (float4*)C;
  int r0 = row0 + rgrp * 2;
  if (r0 < M) {
    C4[(size_t)r0 * 32 + cgrp * 2] =
        make_float4(acc0[0] + b0.x, acc0[1] + b0.y, acc0[2] + b0.z, acc0[3] + b0.w);
    C4[(size_t)r0 * 32 + cgrp * 2 + 1] =
        make_float4(acc0[4] + b1.x, acc0[5] + b1.y, acc0[6] + b1.z, acc0[7] + b1.w);
  }
  if (r0 + 1 < M) {
    C4[(size_t)(r0 + 1) * 32 + cgrp * 2] =
        make_float4(acc1[0] + b0.x, acc1[1] + b0.y, acc1[2] + b0.z, acc1[3] + b0.w);
    C4[(size_t)(r0 + 1) * 32 + cgrp * 2 + 1] =
        make_float4(acc1[4] + b1.x, acc1[5] + b1.y, acc1[6] + b1.z, acc1[7] + b1.w);
  }
}

// ---------------- per-node attention score projections ----------------
// s_dst[n] = h[n] . att[0:128],  s_src[n] = h[n] . att[128:256]

__global__ __launch_bounds__(256) void k_satt(const float* __restrict__ h,
                                              const float* __restrict__ att,
                                              float* __restrict__ sdst,
                                              float* __restrict__ ssrc, int N) {
  int wv = threadIdx.x >> 6, lane = threadIdx.x & 63;
  int n = blockIdx.x * 4 + wv;
  if (n >= N) return;
  float v0 = h[(size_t)n * 128 + lane];
  float v1 = h[(size_t)n * 128 + 64 + lane];
  float pi = v0 * att[lane] + v1 * att[64 + lane];
  float pj = v0 * att[128 + lane] + v1 * att[192 + lane];
#pragma unroll
  for (int off = 32; off; off >>= 1) {
    pi += __shfl_down(pi, off);
    pj += __shfl_down(pj, off);
  }
  if (lane == 0) {
    sdst[n] = pi;
    ssrc[n] = pj;
  }
}

// ---------------- per-dst-node softmax + aggregation + bias + relu ----------------
// one 128-thread block per node

__global__ __launch_bounds__(128) void k_gather(const float* __restrict__ h,
                                                const float* __restrict__ sdst,
                                                const float* __restrict__ ssrc,
                                                const int* __restrict__ csr_src,
                                                const int* __restrict__ offs,
                                                const float* __restrict__ bias,
                                                float* __restrict__ xout) {
  int n = blockIdx.x;
  int tid = threadIdx.x;
  int lane = tid & 63, wv = tid >> 6;
  int start = offs[n], end = offs[n + 1];
  float sdn = sdst[n];
  __shared__ float red[2];

  // phase A: max score
  float m = -INFINITY;
  for (int k = start + tid; k < end; k += 128) {
    float sc = sdn + ssrc[csr_src[k]];
    sc = sc > 0.f ? sc : 0.2f * sc;
    m = fmaxf(m, sc);
  }
#pragma unroll
  for (int off = 32; off; off >>= 1) m = fmaxf(m, __shfl_down(m, off));
  if (lane == 0) red[wv] = m;
  __syncthreads();
  m = fmaxf(red[0], red[1]);
  __syncthreads();

  // phase B: denom
  float ssum = 0.f;
  for (int k = start + tid; k < end; k += 128) {
    float sc = sdn + ssrc[csr_src[k]];
    sc = sc > 0.f ? sc : 0.2f * sc;
    ssum += expf(sc - m);
  }
#pragma unroll
  for (int off = 32; off; off >>= 1) ssum += __shfl_down(ssum, off);
  if (lane == 0) red[wv] = ssum;
  __syncthreads();
  ssum = red[0] + red[1];
  float inv = 1.0f / (ssum + 1e-16f);

  // phase C: aggregate along dim tid
  int d = tid;
  float acc = 0.f;
  for (int k = start; k < end; ++k) {
    int s = csr_src[k];
    float sc = sdn + ssrc[s];
    sc = sc > 0.f ? sc : 0.2f * sc;
    float w = expf(sc - m);
    acc += h[(size_t)s * 128 + d] * w;
  }
  float o = acc * inv + bias[d];
  xout[(size_t)n * 128 + d] = o > 0.f ? o : 0.f;
}

// ---------------- head: out = log_softmax(t @ Wp2 + bp2) ----------------
// Wp2 (128x64) staged in LDS; one wave per node.

__global__ __launch_bounds__(256) void k_head(const float* __restrict__ t,
                                              const float* __restrict__ Wp2,
                                              const float* __restrict__ bp2,
                                              float* __restrict__ out, int N) {
  __shared__ float w2[128 * 64];
  __shared__ float b2s[64];
  int tid = threadIdx.x;
  const float4* Wp24 = (const float4*)Wp2;
  float4* w24 = (float4*)w2;
#pragma unroll
  for (int i = 0; i < 8; ++i) w24[tid + 256 * i] = Wp24[tid + 256 * i];
  if (tid < 64) b2s[tid] = bp2[tid];
  __syncthreads();

  int wv = tid >> 6, lane = tid & 63;
  for (int n = blockIdx.x * 4 + wv; n < N; n += gridDim.x * 4) {
    float t0 = t[(size_t)n * 128 + lane];
    float t1 = t[(size_t)n * 128 + 64 + lane];
    float acc = b2s[lane];
#pragma unroll
    for (int k = 0; k < 64; ++k) acc += __shfl(t0, k) * w2[k * 64 + lane];
#pragma unroll
    for (int k = 0; k < 64; ++k) acc += __shfl(t1, k) * w2[(64 + k) * 64 + lane];

    float mx = acc;
#pragma unroll
    for (int off = 32; off; off >>= 1) mx = fmaxf(mx, __shfl_xor(mx, off));
    float ex = expf(acc - mx);
    float s = ex;
#pragma unroll
    for (int off = 32; off; off >>= 1) s += __shfl_xor(s, off);
    out[(size_t)n * 64 + lane] = acc - mx - logf(s);
  }
}

// ---------------- launch ----------------

extern "C" void kernel_launch(void* const* d_in, const int* in_sizes, int n_in,
                              void* d_out, int out_size, void* d_ws, size_t ws_size,
                              hipStream_t stream) {
  const float* x      = (const float*)d_in[0];
  const int*   ei     = (const int*)d_in[1];
  const float* Ws     = (const float*)d_in[2];
  const float* bs     = (const float*)d_in[3];
  const float* atts   = (const float*)d_in[4];
  const float* biases = (const float*)d_in[5];
  const float* Wp1    = (const float*)d_in[6];
  const float* bp1    = (const float*)d_in[7];
  const float* Wp2    = (const float*)d_in[8];
  const float* bp2    = (const float*)d_in[9];
  float* out = (float*)d_out;

  int N = in_sizes[0] / 128;
  int E = in_sizes[1] / 2;

  float* h    = (float*)d_ws;
  float* xbuf = h + (size_t)N * 128;
  float* sdst = xbuf + (size_t)N * 128;
  float* ssrc = sdst + N;
  int* deg    = (int*)(ssrc + N);
  int* offs   = deg + N;
  int* cursor = offs + N + 1;
  int* csr    = cursor + N;

  // CSR by dst (edge_index is identical every layer — build once per launch)
  hipMemsetAsync(deg, 0, (size_t)N * sizeof(int), stream);
  k_hist<<<(E + 255) / 256, 256, 0, stream>>>(ei, deg, E);
  k_scan<<<1, 1024, 0, stream>>>(deg, offs, N);
  k_copy<<<(N + 255) / 256, 256, 0, stream>>>(offs, cursor, N);
  k_fill<<<(E + 255) / 256, 256, 0, stream>>>(ei, cursor, csr, E);

  const float* xin = x;
  for (int l = 0; l < 3; ++l) {
    k_gemm128<<<(N + 31) / 32, 256, 0, stream>>>(xin, Ws + (size_t)l * 128 * 128,
                                                 bs + (size_t)l * 128, h, N);
    k_satt<<<(N + 3) / 4, 256, 0, stream>>>(h, atts + (size_t)l * 256, sdst, ssrc, N);
    k_gather<<<N, 128, 0, stream>>>(h, sdst, ssrc, csr, offs, biases + (size_t)l * 128, xbuf);
    xin = xbuf;
  }

  // head: t = x @ Wp1 + bp1 (into h), then log_softmax(t @ Wp2 + bp2)
  k_gemm128<<<(N + 31) / 32, 256, 0, stream>>>(xbuf, Wp1, bp1, h, N);
  k_head<<<256, 256, 0, stream>>>(h, Wp2, bp2, out, N);
}

// Round 2
// 532.292 us; speedup vs baseline: 1.4349x; 1.4349x over previous
//
#include <hip/hip_runtime.h>
#include <math.h>

#define D 128
#define OUTD 64
#define BM 128

// ---------------- CSR build ----------------

__global__ void k_hist(const int* __restrict__ ei, int* __restrict__ deg, int E) {
  int e = blockIdx.x * 256 + threadIdx.x;
  if (e < E) atomicAdd(&deg[ei[E + e]], 1);
}

__global__ __launch_bounds__(1024) void k_scan(const int* __restrict__ deg,
                                               int* __restrict__ offs, int N) {
  __shared__ int wsum[16];
  __shared__ int s_carry;
  int tid = threadIdx.x, lane = tid & 63, wv = tid >> 6;
  if (tid == 0) s_carry = 0;
  __syncthreads();
  for (int base = 0; base < N; base += 1024) {
    int i = base + tid;
    int v = (i < N) ? deg[i] : 0;
    int x = v;
#pragma unroll
    for (int off = 1; off < 64; off <<= 1) {
      int t = __shfl_up(x, off);
      if (lane >= off) x += t;
    }
    if (lane == 63) wsum[wv] = x;
    __syncthreads();
    if (wv == 0) {
      int s = (lane < 16) ? wsum[lane] : 0;
#pragma unroll
      for (int off = 1; off < 16; off <<= 1) {
        int t = __shfl_up(s, off);
        if (lane >= off) s += t;
      }
      if (lane < 16) wsum[lane] = s;
    }
    __syncthreads();
    int wexcl = (wv == 0) ? 0 : wsum[wv - 1];
    int excl = s_carry + wexcl + x - v;
    if (i < N) offs[i] = excl;
    __syncthreads();
    if (tid == 1023) s_carry += wsum[15];
    __syncthreads();
  }
  if (tid == 0) offs[N] = s_carry;
}

__global__ void k_copy(const int* __restrict__ a, int* __restrict__ b, int n) {
  int i = blockIdx.x * 256 + threadIdx.x;
  if (i < n) b[i] = a[i];
}

__global__ void k_fill(const int* __restrict__ ei, int* __restrict__ cursor,
                       int* __restrict__ csr_src, int E) {
  int e = blockIdx.x * 256 + threadIdx.x;
  if (e < E) {
    int d = ei[E + e];
    int pos = atomicAdd(&cursor[d], 1);
    csr_src[pos] = ei[e];
  }
}

// ---------------- fold head weights: Wc = Wp1 @ Wp2, bc = bp1 @ Wp2 + bp2 ----------------

__global__ __launch_bounds__(256) void k_fold(const float* __restrict__ Wp1,
                                              const float* __restrict__ bp1,
                                              const float* __restrict__ Wp2,
                                              const float* __restrict__ bp2,
                                              float* __restrict__ Wc,
                                              float* __restrict__ bc) {
  int gid = blockIdx.x * 256 + threadIdx.x;   // 8192 threads
  int i = gid >> 6, j = gid & 63;
  float acc = 0.f;
  for (int k = 0; k < 128; ++k) acc += Wp1[i * 128 + k] * Wp2[k * 64 + j];
  Wc[i * 64 + j] = acc;
  if (gid < 64) {
    float b = bp2[gid];
    for (int k = 0; k < 128; ++k) b += bp1[k] * Wp2[k * 64 + gid];
    bc[gid] = b;
  }
}

// ---------------- GEMM + fused attention score projections ----------------
// H[M x 128] = A @ W + bias; sdst = H . att[0:128]; ssrc = H . att[128:256]
// block 256, BM=128 rows, 8x8 register blocking, x staged transposed in LDS.

__global__ __launch_bounds__(256) void k_gemm_gat(const float* __restrict__ A,
                                                  const float* __restrict__ W,
                                                  const float* __restrict__ bias,
                                                  const float* __restrict__ att,
                                                  float* __restrict__ H,
                                                  float* __restrict__ sdst,
                                                  float* __restrict__ ssrc, int M) {
  __shared__ float xs[32 * 132];   // [kk][row], row-stride 132 (pad: conflict-free b128)
  __shared__ float ws[32 * 128];   // [kk][col]
  int tid = threadIdx.x;
  int row0 = blockIdx.x * BM;
  int cgrp = tid & 15;             // cols cgrp*8 .. +7
  int rgrp = tid >> 4;             // rows rgrp*8 .. +7

  float acc[8][8] = {};

  const float4* A4 = (const float4*)A;
  const float4* W4 = (const float4*)W;
  float4* ws4 = (float4*)ws;

  for (int kt = 0; kt < 4; ++kt) {
    __syncthreads();
#pragma unroll
    for (int i = 0; i < 4; ++i) {
      int idx = tid + 256 * i;          // 0..1023 float4 of x chunk
      int r = idx >> 3, c4 = idx & 7;
      int gr = row0 + r;
      float4 v = (gr < M) ? A4[(size_t)gr * 32 + kt * 8 + c4]
                          : make_float4(0.f, 0.f, 0.f, 0.f);
      int kb = c4 * 4;
      xs[(kb + 0) * 132 + r] = v.x;
      xs[(kb + 1) * 132 + r] = v.y;
      xs[(kb + 2) * 132 + r] = v.z;
      xs[(kb + 3) * 132 + r] = v.w;
    }
#pragma unroll
    for (int i = 0; i < 4; ++i) {
      int idx = tid + 256 * i;
      ws4[idx] = W4[kt * 1024 + idx];
    }
    __syncthreads();
#pragma unroll 8
    for (int kk = 0; kk < 32; ++kk) {
      float4 a0 = *(const float4*)&xs[kk * 132 + rgrp * 8];
      float4 a1 = *(const float4*)&xs[kk * 132 + rgrp * 8 + 4];
      float4 w0 = *(const float4*)&ws[kk * 128 + cgrp * 8];
      float4 w1 = *(const float4*)&ws[kk * 128 + cgrp * 8 + 4];
      float a[8] = {a0.x, a0.y, a0.z, a0.w, a1.x, a1.y, a1.z, a1.w};
      float w[8] = {w0.x, w0.y, w0.z, w0.w, w1.x, w1.y, w1.z, w1.w};
#pragma unroll
      for (int r = 0; r < 8; ++r)
#pragma unroll
        for (int c = 0; c < 8; ++c) acc[r][c] += a[r] * w[c];
    }
  }

  // bias
  float4 b0 = *(const float4*)&bias[cgrp * 8];
  float4 b1 = *(const float4*)&bias[cgrp * 8 + 4];
  float bb[8] = {b0.x, b0.y, b0.z, b0.w, b1.x, b1.y, b1.z, b1.w};
#pragma unroll
  for (int r = 0; r < 8; ++r)
#pragma unroll
    for (int c = 0; c < 8; ++c) acc[r][c] += bb[c];

  // store H
  float4* H4 = (float4*)H;
#pragma unroll
  for (int r = 0; r < 8; ++r) {
    int gr = row0 + rgrp * 8 + r;
    if (gr < M) {
      H4[(size_t)gr * 32 + cgrp * 2] =
          make_float4(acc[r][0], acc[r][1], acc[r][2], acc[r][3]);
      H4[(size_t)gr * 32 + cgrp * 2 + 1] =
          make_float4(acc[r][4], acc[r][5], acc[r][6], acc[r][7]);
    }
  }

  // fused score projections: per row, reduce acc . att over the 16 col-lanes
  float4 ai0 = *(const float4*)&att[cgrp * 8];
  float4 ai1 = *(const float4*)&att[cgrp * 8 + 4];
  float4 aj0 = *(const float4*)&att[128 + cgrp * 8];
  float4 aj1 = *(const float4*)&att[128 + cgrp * 8 + 4];
  float ai[8] = {ai0.x, ai0.y, ai0.z, ai0.w, ai1.x, ai1.y, ai1.z, ai1.w};
  float aj[8] = {aj0.x, aj0.y, aj0.z, aj0.w, aj1.x, aj1.y, aj1.z, aj1.w};
#pragma unroll
  for (int r = 0; r < 8; ++r) {
    float pi = 0.f, pj = 0.f;
#pragma unroll
    for (int c = 0; c < 8; ++c) {
      pi += acc[r][c] * ai[c];
      pj += acc[r][c] * aj[c];
    }
#pragma unroll
    for (int off = 1; off < 16; off <<= 1) {
      pi += __shfl_xor(pi, off);
      pj += __shfl_xor(pj, off);
    }
    if (cgrp == 0) {
      int gr = row0 + rgrp * 8 + r;
      if (gr < M) {
        sdst[gr] = pi;
        ssrc[gr] = pj;
      }
    }
  }
}

// ---------------- softmax + aggregation, wave per node ----------------

__global__ __launch_bounds__(256) void k_gather(const float* __restrict__ H,
                                                const float* __restrict__ sdst,
                                                const float* __restrict__ ssrc,
                                                const int* __restrict__ csr,
                                                const int* __restrict__ offs,
                                                const float* __restrict__ bias,
                                                float* __restrict__ xout, int N) {
  int wv = threadIdx.x >> 6, lane = threadIdx.x & 63;
  int n = blockIdx.x * 4 + wv;
  if (n >= N) return;
  int start = offs[n];
  int cnt = offs[n + 1] - start;
  float sdn = sdst[n];
  const float2* H2 = (const float2*)H;

  float2 acc = make_float2(0.f, 0.f);
  float inv;

  if (cnt <= 64) {
    int s = 0;
    float sc = -INFINITY;
    if (lane < cnt) {
      s = csr[start + lane];
      float e = sdn + ssrc[s];
      sc = e > 0.f ? e : 0.2f * e;
    }
    float m = sc;
#pragma unroll
    for (int off = 32; off; off >>= 1) m = fmaxf(m, __shfl_xor(m, off));
    float w = (lane < cnt) ? expf(sc - m) : 0.f;
    float ssum = w;
#pragma unroll
    for (int off = 32; off; off >>= 1) ssum += __shfl_xor(ssum, off);
    inv = 1.0f / (ssum + 1e-16f);
    for (int k = 0; k < cnt; ++k) {
      float wk = __shfl(w, k);
      int sk = __shfl(s, k);
      float2 hv = H2[(size_t)sk * 64 + lane];
      acc.x += wk * hv.x;
      acc.y += wk * hv.y;
    }
  } else {
    int end = start + cnt;
    float m = -INFINITY;
    for (int k = start + lane; k < end; k += 64) {
      float e = sdn + ssrc[csr[k]];
      e = e > 0.f ? e : 0.2f * e;
      m = fmaxf(m, e);
    }
#pragma unroll
    for (int off = 32; off; off >>= 1) m = fmaxf(m, __shfl_xor(m, off));
    float ssum = 0.f;
    for (int k = start + lane; k < end; k += 64) {
      float e = sdn + ssrc[csr[k]];
      e = e > 0.f ? e : 0.2f * e;
      ssum += expf(e - m);
    }
#pragma unroll
    for (int off = 32; off; off >>= 1) ssum += __shfl_xor(ssum, off);
    inv = 1.0f / (ssum + 1e-16f);
    for (int k = start; k < end; ++k) {
      int sk = csr[k];
      float e = sdn + ssrc[sk];
      e = e > 0.f ? e : 0.2f * e;
      float wk = expf(e - m);
      float2 hv = H2[(size_t)sk * 64 + lane];
      acc.x += wk * hv.x;
      acc.y += wk * hv.y;
    }
  }

  float2 b = ((const float2*)bias)[lane];
  float ox = acc.x * inv + b.x;
  float oy = acc.y * inv + b.y;
  ox = ox > 0.f ? ox : 0.f;
  oy = oy > 0.f ? oy : 0.f;
  ((float2*)xout)[(size_t)n * 64 + lane] = make_float2(ox, oy);
}

// ---------------- head: out = log_softmax(x @ Wc + bc), thread per node ----------------

__global__ __launch_bounds__(128) void k_head2(const float* __restrict__ X,
                                               const float* __restrict__ Wc,
                                               const float* __restrict__ bc,
                                               float* __restrict__ out, int N) {
  __shared__ float xs[128 * 33];
  int tid = threadIdx.x;
  int row0 = blockIdx.x * 128;
  int n = row0 + tid;

  float acc[64];
#pragma unroll
  for (int j = 0; j < 64; ++j) acc[j] = 0.f;

  const float4* X4 = (const float4*)X;
  for (int kt = 0; kt < 4; ++kt) {
    __syncthreads();
#pragma unroll
    for (int i = 0; i < 8; ++i) {
      int idx = tid + 128 * i;        // 0..1023 float4
      int r = idx >> 3, c4 = idx & 7;
      int gr = row0 + r;
      float4 v = (gr < N) ? X4[(size_t)gr * 32 + kt * 8 + c4]
                          : make_float4(0.f, 0.f, 0.f, 0.f);
      int kb = c4 * 4;
      xs[r * 33 + kb + 0] = v.x;
      xs[r * 33 + kb + 1] = v.y;
      xs[r * 33 + kb + 2] = v.z;
      xs[r * 33 + kb + 3] = v.w;
    }
    __syncthreads();
#pragma unroll 4
    for (int kk = 0; kk < 32; ++kk) {
      float a = xs[tid * 33 + kk];
      const float* wr = Wc + (kt * 32 + kk) * 64;   // wave-uniform -> s_loads
#pragma unroll
      for (int j = 0; j < 64; ++j) acc[j] = fmaf(a, wr[j], acc[j]);
    }
  }

#pragma unroll
  for (int j = 0; j < 64; ++j) acc[j] += bc[j];

  float mx = -INFINITY;
#pragma unroll
  for (int j = 0; j < 64; ++j) mx = fmaxf(mx, acc[j]);
  float s = 0.f;
#pragma unroll
  for (int j = 0; j < 64; ++j) s += expf(acc[j] - mx);
  float ls = mx + logf(s);

  if (n < N) {
    float4* o4 = (float4*)(out + (size_t)n * 64);
#pragma unroll
    for (int j4 = 0; j4 < 16; ++j4)
      o4[j4] = make_float4(acc[j4 * 4] - ls, acc[j4 * 4 + 1] - ls,
                           acc[j4 * 4 + 2] - ls, acc[j4 * 4 + 3] - ls);
  }
}

// ---------------- launch ----------------

extern "C" void kernel_launch(void* const* d_in, const int* in_sizes, int n_in,
                              void* d_out, int out_size, void* d_ws, size_t ws_size,
                              hipStream_t stream) {
  const float* x      = (const float*)d_in[0];
  const int*   ei     = (const int*)d_in[1];
  const float* Ws     = (const float*)d_in[2];
  const float* bs     = (const float*)d_in[3];
  const float* atts   = (const float*)d_in[4];
  const float* biases = (const float*)d_in[5];
  const float* Wp1    = (const float*)d_in[6];
  const float* bp1    = (const float*)d_in[7];
  const float* Wp2    = (const float*)d_in[8];
  const float* bp2    = (const float*)d_in[9];
  float* out = (float*)d_out;

  int N = in_sizes[0] / 128;
  int E = in_sizes[1] / 2;

  float* h    = (float*)d_ws;
  float* xbuf = h + (size_t)N * 128;
  float* sdst = xbuf + (size_t)N * 128;
  float* ssrc = sdst + N;
  int* deg    = (int*)(ssrc + N);
  int* offs   = deg + N;
  int* cursor = offs + N + 1;
  int* csr    = cursor + N;
  float* Wc   = (float*)(csr + E);
  float* bc   = Wc + 128 * 64;

  // fold head weights (independent of everything else)
  k_fold<<<32, 256, 0, stream>>>(Wp1, bp1, Wp2, bp2, Wc, bc);

  // CSR by dst
  hipMemsetAsync(deg, 0, (size_t)N * sizeof(int), stream);
  k_hist<<<(E + 255) / 256, 256, 0, stream>>>(ei, deg, E);
  k_scan<<<1, 1024, 0, stream>>>(deg, offs, N);
  k_copy<<<(N + 255) / 256, 256, 0, stream>>>(offs, cursor, N);
  k_fill<<<(E + 255) / 256, 256, 0, stream>>>(ei, cursor, csr, E);

  const float* xin = x;
  for (int l = 0; l < 3; ++l) {
    k_gemm_gat<<<(N + BM - 1) / BM, 256, 0, stream>>>(
        xin, Ws + (size_t)l * 128 * 128, bs + (size_t)l * 128,
        atts + (size_t)l * 256, h, sdst, ssrc, N);
    k_gather<<<(N + 3) / 4, 256, 0, stream>>>(h, sdst, ssrc, csr, offs,
                                              biases + (size_t)l * 128, xbuf, N);
    xin = xbuf;
  }

  k_head2<<<(N + 127) / 128, 128, 0, stream>>>(xbuf, Wc, bc, out, N);
}

// Round 3
// 420.586 us; speedup vs baseline: 1.8161x; 1.2656x over previous
//
#include <hip/hip_runtime.h>
#include <math.h>

#define D 128
#define OUTD 64
#define BM 128

static __device__ __forceinline__ float bf2f(unsigned short u) {
  return __uint_as_float(((unsigned int)u) << 16);
}
static __device__ __forceinline__ unsigned short f2bf(float f) {
  unsigned int u = __float_as_uint(f);
  u = (u + 0x7fff + ((u >> 16) & 1)) >> 16;   // RNE
  return (unsigned short)u;
}

// ---------------- CSR build ----------------

__global__ void k_hist(const int* __restrict__ ei, int* __restrict__ deg, int E) {
  int e = blockIdx.x * 256 + threadIdx.x;
  if (e < E) atomicAdd(&deg[ei[E + e]], 1);
}

// block-local exclusive scan of 1024 elems; partial[b] = block total
__global__ __launch_bounds__(1024) void k_scan1(const int* __restrict__ deg,
                                                int* __restrict__ offs,
                                                int* __restrict__ partial, int N) {
  __shared__ int wsum[16];
  int tid = threadIdx.x, lane = tid & 63, wv = tid >> 6;
  int i = blockIdx.x * 1024 + tid;
  int v = (i < N) ? deg[i] : 0;
  int x = v;
#pragma unroll
  for (int off = 1; off < 64; off <<= 1) {
    int t = __shfl_up(x, off);
    if (lane >= off) x += t;
  }
  if (lane == 63) wsum[wv] = x;
  __syncthreads();
  if (wv == 0) {
    int s = (lane < 16) ? wsum[lane] : 0;
#pragma unroll
    for (int off = 1; off < 16; off <<= 1) {
      int t = __shfl_up(s, off);
      if (lane >= off) s += t;
    }
    if (lane < 16) wsum[lane] = s;
  }
  __syncthreads();
  int wexcl = (wv == 0) ? 0 : wsum[wv - 1];
  if (i < N) offs[i] = wexcl + x - v;
  if (tid == 0) partial[blockIdx.x] = wsum[15];
}

// single-block exclusive scan (for partials, nb <= 1024)
__global__ __launch_bounds__(1024) void k_scan(const int* __restrict__ deg,
                                               int* __restrict__ offs, int N) {
  __shared__ int wsum[16];
  __shared__ int s_carry;
  int tid = threadIdx.x, lane = tid & 63, wv = tid >> 6;
  if (tid == 0) s_carry = 0;
  __syncthreads();
  for (int base = 0; base < N; base += 1024) {
    int i = base + tid;
    int v = (i < N) ? deg[i] : 0;
    int x = v;
#pragma unroll
    for (int off = 1; off < 64; off <<= 1) {
      int t = __shfl_up(x, off);
      if (lane >= off) x += t;
    }
    if (lane == 63) wsum[wv] = x;
    __syncthreads();
    if (wv == 0) {
      int s = (lane < 16) ? wsum[lane] : 0;
#pragma unroll
      for (int off = 1; off < 16; off <<= 1) {
        int t = __shfl_up(s, off);
        if (lane >= off) s += t;
      }
      if (lane < 16) wsum[lane] = s;
    }
    __syncthreads();
    int wexcl = (wv == 0) ? 0 : wsum[wv - 1];
    if (i < N) offs[i] = s_carry + wexcl + x - v;
    __syncthreads();
    if (tid == 1023) s_carry += wsum[15];
    __syncthreads();
  }
  if (tid == 0) offs[N] = s_carry;
}

__global__ __launch_bounds__(1024) void k_add(int* __restrict__ offs,
                                              const int* __restrict__ partialx, int N) {
  int i = blockIdx.x * 1024 + threadIdx.x;
  int a = partialx[blockIdx.x];
  if (i < N) offs[i] += a;
}

// atomicAdd directly on offs: afterwards offs[n] = END of node n's range.
__global__ void k_fill(const int* __restrict__ ei, int* __restrict__ offs,
                       int* __restrict__ csr_src, int E) {
  int e = blockIdx.x * 256 + threadIdx.x;
  if (e < E) {
    int d = ei[E + e];
    int pos = atomicAdd(&offs[d], 1);
    csr_src[pos] = ei[e];
  }
}

// ---------------- fold head weights: Wc = Wp1 @ Wp2, bc = bp1 @ Wp2 + bp2 ----------------

__global__ __launch_bounds__(256) void k_fold(const float* __restrict__ Wp1,
                                              const float* __restrict__ bp1,
                                              const float* __restrict__ Wp2,
                                              const float* __restrict__ bp2,
                                              float* __restrict__ Wc,
                                              float* __restrict__ bc) {
  int gid = blockIdx.x * 256 + threadIdx.x;   // 8192 threads
  int i = gid >> 6, j = gid & 63;
  float acc = 0.f;
  for (int k = 0; k < 128; ++k) acc += Wp1[i * 128 + k] * Wp2[k * 64 + j];
  Wc[i * 64 + j] = acc;
  if (gid < 64) {
    float b = bp2[gid];
    for (int k = 0; k < 128; ++k) b += bp1[k] * Wp2[k * 64 + gid];
    bc[gid] = b;
  }
}

// ---------------- GEMM + fused attention score projections ----------------
// H(bf16)[M x 128] = A @ W + bias; sdst = H.att[0:128]; ssrc = H.att[128:256]

__global__ __launch_bounds__(256) void k_gemm_gat(const float* __restrict__ A,
                                                  const float* __restrict__ W,
                                                  const float* __restrict__ bias,
                                                  const float* __restrict__ att,
                                                  unsigned short* __restrict__ H,
                                                  float* __restrict__ sdst,
                                                  float* __restrict__ ssrc, int M) {
  __shared__ float xs[32 * 132];   // [kk][row], pad 132
  __shared__ float ws[32 * 128];   // [kk][col]
  int tid = threadIdx.x;
  int row0 = blockIdx.x * BM;
  int cgrp = tid & 15;             // cols cgrp*8 .. +7
  int rgrp = tid >> 4;             // rows rgrp*8 .. +7

  float acc[8][8] = {};

  const float4* A4 = (const float4*)A;
  const float4* W4 = (const float4*)W;
  float4* ws4 = (float4*)ws;

  for (int kt = 0; kt < 4; ++kt) {
    __syncthreads();
#pragma unroll
    for (int i = 0; i < 4; ++i) {
      int idx = tid + 256 * i;
      int r = idx >> 3, c4 = idx & 7;
      int gr = row0 + r;
      float4 v = (gr < M) ? A4[(size_t)gr * 32 + kt * 8 + c4]
                          : make_float4(0.f, 0.f, 0.f, 0.f);
      int kb = c4 * 4;
      xs[(kb + 0) * 132 + r] = v.x;
      xs[(kb + 1) * 132 + r] = v.y;
      xs[(kb + 2) * 132 + r] = v.z;
      xs[(kb + 3) * 132 + r] = v.w;
    }
#pragma unroll
    for (int i = 0; i < 4; ++i) {
      int idx = tid + 256 * i;
      ws4[idx] = W4[kt * 1024 + idx];
    }
    __syncthreads();
#pragma unroll 8
    for (int kk = 0; kk < 32; ++kk) {
      float4 a0 = *(const float4*)&xs[kk * 132 + rgrp * 8];
      float4 a1 = *(const float4*)&xs[kk * 132 + rgrp * 8 + 4];
      float4 w0 = *(const float4*)&ws[kk * 128 + cgrp * 8];
      float4 w1 = *(const float4*)&ws[kk * 128 + cgrp * 8 + 4];
      float a[8] = {a0.x, a0.y, a0.z, a0.w, a1.x, a1.y, a1.z, a1.w};
      float w[8] = {w0.x, w0.y, w0.z, w0.w, w1.x, w1.y, w1.z, w1.w};
#pragma unroll
      for (int r = 0; r < 8; ++r)
#pragma unroll
        for (int c = 0; c < 8; ++c) acc[r][c] += a[r] * w[c];
    }
  }

  float4 b0 = *(const float4*)&bias[cgrp * 8];
  float4 b1 = *(const float4*)&bias[cgrp * 8 + 4];
  float bb[8] = {b0.x, b0.y, b0.z, b0.w, b1.x, b1.y, b1.z, b1.w};
#pragma unroll
  for (int r = 0; r < 8; ++r)
#pragma unroll
    for (int c = 0; c < 8; ++c) acc[r][c] += bb[c];

  // store H as bf16 (row = 128 bf16 = 32 ushort4)
  ushort4* H4 = (ushort4*)H;
#pragma unroll
  for (int r = 0; r < 8; ++r) {
    int gr = row0 + rgrp * 8 + r;
    if (gr < M) {
      ushort4 p0, p1;
      p0.x = f2bf(acc[r][0]); p0.y = f2bf(acc[r][1]);
      p0.z = f2bf(acc[r][2]); p0.w = f2bf(acc[r][3]);
      p1.x = f2bf(acc[r][4]); p1.y = f2bf(acc[r][5]);
      p1.z = f2bf(acc[r][6]); p1.w = f2bf(acc[r][7]);
      H4[(size_t)gr * 32 + cgrp * 2] = p0;
      H4[(size_t)gr * 32 + cgrp * 2 + 1] = p1;
    }
  }

  // fused score projections (fp32, from the fp32 accumulators)
  float4 ai0 = *(const float4*)&att[cgrp * 8];
  float4 ai1 = *(const float4*)&att[cgrp * 8 + 4];
  float4 aj0 = *(const float4*)&att[128 + cgrp * 8];
  float4 aj1 = *(const float4*)&att[128 + cgrp * 8 + 4];
  float ai[8] = {ai0.x, ai0.y, ai0.z, ai0.w, ai1.x, ai1.y, ai1.z, ai1.w};
  float aj[8] = {aj0.x, aj0.y, aj0.z, aj0.w, aj1.x, aj1.y, aj1.z, aj1.w};
#pragma unroll
  for (int r = 0; r < 8; ++r) {
    float pi = 0.f, pj = 0.f;
#pragma unroll
    for (int c = 0; c < 8; ++c) {
      pi += acc[r][c] * ai[c];
      pj += acc[r][c] * aj[c];
    }
#pragma unroll
    for (int off = 1; off < 16; off <<= 1) {
      pi += __shfl_xor(pi, off);
      pj += __shfl_xor(pj, off);
    }
    if (cgrp == 0) {
      int gr = row0 + rgrp * 8 + r;
      if (gr < M) {
        sdst[gr] = pi;
        ssrc[gr] = pj;
      }
    }
  }
}

// ---------------- softmax + aggregation: 2 nodes per wave, online softmax ----------------
// offs holds END offsets (start of node n = offs[n-1], or 0).

__global__ __launch_bounds__(256) void k_gather(const ushort4* __restrict__ H4,
                                                const float* __restrict__ sdst,
                                                const float* __restrict__ ssrc,
                                                const int* __restrict__ csr,
                                                const int* __restrict__ offs,
                                                const float* __restrict__ bias,
                                                float* __restrict__ xout, int N) {
  int tid = threadIdx.x;
  int wv = tid >> 6, lane = tid & 63, sub = lane >> 5, l32 = lane & 31;
  int n = blockIdx.x * 8 + wv * 2 + sub;
  bool valid = (n < N);
  int end = valid ? offs[n] : 0;
  int start = (valid && n > 0) ? offs[n - 1] : 0;
  float sdn = valid ? sdst[n] : 0.f;

  float m = -INFINITY, ssum = 0.f;
  float4 acc = make_float4(0.f, 0.f, 0.f, 0.f);

  for (int base = start; base < end; base += 32) {
    int k = base + l32;
    int s = 0;
    float sc = -INFINITY;
    if (k < end) {
      s = csr[k];
      float e = sdn + ssrc[s];
      sc = e > 0.f ? e : 0.2f * e;
    }
    float cm = sc;
#pragma unroll
    for (int off = 16; off; off >>= 1) cm = fmaxf(cm, __shfl_xor(cm, off));
    float nm = fmaxf(m, cm);
    float scale = __expf(m - nm);          // first chunk: exp(-inf)=0, acc/ssum are 0
    acc.x *= scale; acc.y *= scale; acc.z *= scale; acc.w *= scale;
    float w = (k < end) ? __expf(sc - nm) : 0.f;
    float cs = w;
#pragma unroll
    for (int off = 16; off; off >>= 1) cs += __shfl_xor(cs, off);
    ssum = ssum * scale + cs;
    m = nm;
    int cc = end - base; if (cc > 32) cc = 32;
    for (int j = 0; j < cc; ++j) {
      float wj = __shfl(w, sub * 32 + j);
      int sj = __shfl(s, sub * 32 + j);
      ushort4 hv = H4[(size_t)sj * 32 + l32];
      acc.x += wj * bf2f(hv.x);
      acc.y += wj * bf2f(hv.y);
      acc.z += wj * bf2f(hv.z);
      acc.w += wj * bf2f(hv.w);
    }
  }

  if (valid) {
    float inv = 1.0f / (ssum + 1e-16f);
    float4 b = ((const float4*)bias)[l32];
    float4 o;
    o.x = fmaxf(acc.x * inv + b.x, 0.f);
    o.y = fmaxf(acc.y * inv + b.y, 0.f);
    o.z = fmaxf(acc.z * inv + b.z, 0.f);
    o.w = fmaxf(acc.w * inv + b.w, 0.f);
    ((float4*)xout)[(size_t)n * 32 + l32] = o;
  }
}

// ---------------- head: out = log_softmax(x @ Wc + bc), thread per node ----------------

__global__ __launch_bounds__(128) void k_head2(const float* __restrict__ X,
                                               const float* __restrict__ Wc,
                                               const float* __restrict__ bc,
                                               float* __restrict__ out, int N) {
  __shared__ float xs[128 * 33];
  int tid = threadIdx.x;
  int row0 = blockIdx.x * 128;
  int n = row0 + tid;

  float acc[64];
#pragma unroll
  for (int j = 0; j < 64; ++j) acc[j] = 0.f;

  const float4* X4 = (const float4*)X;
  for (int kt = 0; kt < 4; ++kt) {
    __syncthreads();
#pragma unroll
    for (int i = 0; i < 8; ++i) {
      int idx = tid + 128 * i;
      int r = idx >> 3, c4 = idx & 7;
      int gr = row0 + r;
      float4 v = (gr < N) ? X4[(size_t)gr * 32 + kt * 8 + c4]
                          : make_float4(0.f, 0.f, 0.f, 0.f);
      int kb = c4 * 4;
      xs[r * 33 + kb + 0] = v.x;
      xs[r * 33 + kb + 1] = v.y;
      xs[r * 33 + kb + 2] = v.z;
      xs[r * 33 + kb + 3] = v.w;
    }
    __syncthreads();
#pragma unroll 4
    for (int kk = 0; kk < 32; ++kk) {
      float a = xs[tid * 33 + kk];
      const float* wr = Wc + (kt * 32 + kk) * 64;   // wave-uniform -> s_loads
#pragma unroll
      for (int j = 0; j < 64; ++j) acc[j] = fmaf(a, wr[j], acc[j]);
    }
  }

#pragma unroll
  for (int j = 0; j < 64; ++j) acc[j] += bc[j];

  float mx = -INFINITY;
#pragma unroll
  for (int j = 0; j < 64; ++j) mx = fmaxf(mx, acc[j]);
  float s = 0.f;
#pragma unroll
  for (int j = 0; j < 64; ++j) s += expf(acc[j] - mx);
  float ls = mx + logf(s);

  if (n < N) {
    float4* o4 = (float4*)(out + (size_t)n * 64);
#pragma unroll
    for (int j4 = 0; j4 < 16; ++j4)
      o4[j4] = make_float4(acc[j4 * 4] - ls, acc[j4 * 4 + 1] - ls,
                           acc[j4 * 4 + 2] - ls, acc[j4 * 4 + 3] - ls);
  }
}

// ---------------- launch ----------------

extern "C" void kernel_launch(void* const* d_in, const int* in_sizes, int n_in,
                              void* d_out, int out_size, void* d_ws, size_t ws_size,
                              hipStream_t stream) {
  const float* x      = (const float*)d_in[0];
  const int*   ei     = (const int*)d_in[1];
  const float* Ws     = (const float*)d_in[2];
  const float* bs     = (const float*)d_in[3];
  const float* atts   = (const float*)d_in[4];
  const float* biases = (const float*)d_in[5];
  const float* Wp1    = (const float*)d_in[6];
  const float* bp1    = (const float*)d_in[7];
  const float* Wp2    = (const float*)d_in[8];
  const float* bp2    = (const float*)d_in[9];
  float* out = (float*)d_out;

  int N = in_sizes[0] / 128;
  int E = in_sizes[1] / 2;
  int Np = (N + 3) & ~3;
  int nb = (N + 1023) / 1024;

  float* xbuf = (float*)d_ws;                       // N*128 f32
  unsigned short* H = (unsigned short*)(xbuf + (size_t)N * 128);  // N*128 bf16
  float* sdst = (float*)(H + (size_t)Np * 128);
  float* ssrc = sdst + Np;
  float* Wc   = ssrc + Np;
  float* bc   = Wc + 128 * 64;
  int* deg    = (int*)(bc + 64);
  int* offs   = deg + Np;
  int* partial  = offs + Np;
  int* partialx = partial + 1024;
  int* csr      = partialx + 1028;

  // fold head weights
  k_fold<<<32, 256, 0, stream>>>(Wp1, bp1, Wp2, bp2, Wc, bc);

  // CSR by dst
  hipMemsetAsync(deg, 0, (size_t)N * sizeof(int), stream);
  k_hist<<<(E + 255) / 256, 256, 0, stream>>>(ei, deg, E);
  k_scan1<<<nb, 1024, 0, stream>>>(deg, offs, partial, N);
  k_scan<<<1, 1024, 0, stream>>>(partial, partialx, nb);
  k_add<<<nb, 1024, 0, stream>>>(offs, partialx, N);
  k_fill<<<(E + 255) / 256, 256, 0, stream>>>(ei, offs, csr, E);   // offs -> ends

  const float* xin = x;
  for (int l = 0; l < 3; ++l) {
    k_gemm_gat<<<(N + BM - 1) / BM, 256, 0, stream>>>(
        xin, Ws + (size_t)l * 128 * 128, bs + (size_t)l * 128,
        atts + (size_t)l * 256, H, sdst, ssrc, N);
    k_gather<<<(N + 7) / 8, 256, 0, stream>>>((const ushort4*)H, sdst, ssrc, csr, offs,
                                              biases + (size_t)l * 128, xbuf, N);
    xin = xbuf;
  }

  k_head2<<<(N + 127) / 128, 128, 0, stream>>>(xbuf, Wc, bc, out, N);
}